// Round 4
// baseline (114.217 us; speedup 1.0000x reference)
//
#include <hip/hip_runtime.h>

// ---------------------------------------------------------------------------
// out[i] = exp(cumsum_{j<k} log1p(-beta_j)),  k = clip(round(t[i]), 0, 1000)
// beta_j = a + d*j is linear, so clog(k) = -(S1 + S2/2 + S3/3) + O(1e-5) is a
// closed-form degree-4 polynomial in k (power sums), evaluated by Horner.
// Truncation + float Horner error <= ~1e-5 absolute in exp(clog); threshold 2e-2.
// ---------------------------------------------------------------------------
namespace {
constexpr double a_  = 1e-4;
constexpr double d_  = (20.0 / 1000.0 - 1e-4) / 999.0;

constexpr double A1d = (a_ - d_ / 2.0)
                     + (a_ * a_ - a_ * d_ + d_ * d_ / 6.0) / 2.0
                     + (a_ * a_ * a_ - 1.5 * a_ * a_ * d_ + 0.5 * a_ * d_ * d_) / 3.0;
constexpr double A2d = d_ / 2.0
                     + (a_ * d_ - d_ * d_ / 2.0) / 2.0
                     + (1.5 * a_ * a_ * d_ - 1.5 * a_ * d_ * d_ + 0.25 * d_ * d_ * d_) / 3.0;
constexpr double A3d = d_ * d_ / 6.0
                     + (a_ * d_ * d_ - 0.5 * d_ * d_ * d_) / 3.0;
constexpr double A4d = d_ * d_ * d_ / 12.0;

constexpr float A1 = (float)A1d;
constexpr float A2 = (float)A2d;
constexpr float A3 = (float)A3d;
constexpr float A4 = (float)A4d;
constexpr float LOG2E = 1.4426950408889634f;
}

// Native clang vector type — required by __builtin_nontemporal_load/store
// (HIP's float4 is a struct and is rejected).
typedef float vf4 __attribute__((ext_vector_type(4)));

__device__ __forceinline__ float alpha_bar(float v) {
    float k = __builtin_rintf(v);             // v_rndne_f32 = jnp.round semantics
    k = fminf(fmaxf(k, 0.0f), 1000.0f);
    float p = fmaf(k, A4, A3);
    p = fmaf(k, p, A2);
    p = fmaf(k, p, A1);
    return exp2f(-k * p * LOG2E);
}

// Grid-stride over float4s; nontemporal (streaming) loads/stores — no reuse,
// so skip cache allocation on both streams.
__global__ __launch_bounds__(256)
void ddpm_alpha_bar(const float* __restrict__ t,
                    float* __restrict__ out,
                    int n) {
    const int n4     = n >> 2;
    const int stride = gridDim.x * blockDim.x;
    const vf4* __restrict__ t4 = (const vf4*)t;
    vf4*       __restrict__ o4 = (vf4*)out;

    for (int i = blockIdx.x * blockDim.x + threadIdx.x; i < n4; i += stride) {
        vf4 v = __builtin_nontemporal_load(&t4[i]);
        vf4 r;
        r.x = alpha_bar(v.x);
        r.y = alpha_bar(v.y);
        r.z = alpha_bar(v.z);
        r.w = alpha_bar(v.w);
        __builtin_nontemporal_store(r, &o4[i]);
    }

    // Tail (n % 4) — scalar.
    const int base = n4 << 2;
    int gid = blockIdx.x * blockDim.x + threadIdx.x;
    if (gid < n - base) {
        out[base + gid] = alpha_bar(t[base + gid]);
    }
}

extern "C" void kernel_launch(void* const* d_in, const int* in_sizes, int n_in,
                              void* d_out, int out_size, void* d_ws, size_t ws_size,
                              hipStream_t stream) {
    const float* t = (const float*)d_in[0];
    float* out     = (float*)d_out;
    const int n    = in_sizes[0];

    // ~2 float4 per thread: 16.77M/4 / 256 / 2 ≈ 8192 blocks (32/CU).
    int n4     = (n + 3) >> 2;
    int blocks = (n4 + 2 * 256 - 1) / (2 * 256);
    if (blocks < 1) blocks = 1;
    if (blocks > 65535) blocks = 65535;
    ddpm_alpha_bar<<<blocks, 256, 0, stream>>>(t, out, n);
}

// Round 5
// 107.877 us; speedup vs baseline: 1.0588x; 1.0588x over previous
//
#include <hip/hip_runtime.h>

// ---------------------------------------------------------------------------
// out[i] = exp(cumsum_{j<k} log1p(-beta_j)),  k = clip(round(t[i]), 0, 1000)
// beta_j = a + d*j is linear, so clog(k) = -(S1 + S2/2 + S3/3) + O(1e-5) is a
// closed-form degree-4 polynomial in k (power sums), evaluated by Horner.
// Truncation + float Horner error <= ~1e-5 absolute in exp(clog); threshold 2e-2.
//
// R4 post-mortem: nontemporal load/store + grid-stride regressed 109->114 us;
// reverted to the plain one-float4-per-thread form (best measured, R2).
// ---------------------------------------------------------------------------
namespace {
constexpr double a_  = 1e-4;
constexpr double d_  = (20.0 / 1000.0 - 1e-4) / 999.0;

constexpr double A1d = (a_ - d_ / 2.0)
                     + (a_ * a_ - a_ * d_ + d_ * d_ / 6.0) / 2.0
                     + (a_ * a_ * a_ - 1.5 * a_ * a_ * d_ + 0.5 * a_ * d_ * d_) / 3.0;
constexpr double A2d = d_ / 2.0
                     + (a_ * d_ - d_ * d_ / 2.0) / 2.0
                     + (1.5 * a_ * a_ * d_ - 1.5 * a_ * d_ * d_ + 0.25 * d_ * d_ * d_) / 3.0;
constexpr double A3d = d_ * d_ / 6.0
                     + (a_ * d_ * d_ - 0.5 * d_ * d_ * d_) / 3.0;
constexpr double A4d = d_ * d_ * d_ / 12.0;

constexpr float A1 = (float)A1d;
constexpr float A2 = (float)A2d;
constexpr float A3 = (float)A3d;
constexpr float A4 = (float)A4d;
constexpr float LOG2E = 1.4426950408889634f;
}

__device__ __forceinline__ float alpha_bar(float v) {
    float k = __builtin_rintf(v);             // v_rndne_f32 = jnp.round semantics
    k = fminf(fmaxf(k, 0.0f), 1000.0f);
    float p = fmaf(k, A4, A3);
    p = fmaf(k, p, A2);
    p = fmaf(k, p, A1);
    return exp2f(-k * p * LOG2E);
}

__global__ __launch_bounds__(256)
void ddpm_alpha_bar(const float* __restrict__ t,
                    float* __restrict__ out,
                    int n) {
    const int gid = blockIdx.x * blockDim.x + threadIdx.x;
    const int n4  = n >> 2;

    if (gid < n4) {
        float4 v = ((const float4*)t)[gid];
        float4 r;
        r.x = alpha_bar(v.x);
        r.y = alpha_bar(v.y);
        r.z = alpha_bar(v.z);
        r.w = alpha_bar(v.w);
        ((float4*)out)[gid] = r;
    }

    // Tail (n not divisible by 4).
    int tail = n - (n4 << 2);
    if (gid < tail) {
        int k = (n4 << 2) + gid;
        out[k] = alpha_bar(t[k]);
    }
}

extern "C" void kernel_launch(void* const* d_in, const int* in_sizes, int n_in,
                              void* d_out, int out_size, void* d_ws, size_t ws_size,
                              hipStream_t stream) {
    const float* t = (const float*)d_in[0];
    float* out     = (float*)d_out;
    const int n    = in_sizes[0];

    int n4     = (n + 3) >> 2;
    int blocks = (n4 + 255) / 256;
    if (blocks < 1) blocks = 1;
    ddpm_alpha_bar<<<blocks, 256, 0, stream>>>(t, out, n);
}